// Round 4
// baseline (612.735 us; speedup 1.0000x reference)
//
#include <hip/hip_runtime.h>

// VQ-VAE codebook quantization — R16: zeros-early one-hot (overlap the
// zero-stream with the screen; dependent writes shrink to 16B/pair).
// x: (4096, 1024) f32; codebook: (128, 256, 8) f32.
// out = [cw_embed (4096*1024 f32) | one_hot (4096*128*256 f32)].
//
// Post-mortems R13-R15: all three screen-cost reducers regressed
// (SMEM +42, readlane +25, BPT=4 +12 — the last genuinely halved LDS
// screen traffic and still lost). The "LDS-bound serial screen" theory is
// dead. Remaining model: grid is exactly co-resident (1024 blocks, 4/CU),
// so the GPU is phase-locked — HBM idles during the screen, then a ~90us
// drain. The lever is HBM idle time, not screen cost.
//
// R16: one-hot is 99.6% zeros and zeros don't depend on the screen.
// Interleave the 1KB zero-bursts into the screen k-loop (1 burst per 2 k,
// 128 bursts/wave = same rows as R8's burst loop). After screen + fp64
// repair + embed write: s_waitcnt vmcnt(0) (zeros for this wave's rows
// were written BY this wave -> same-wave ordering via vmcnt retire at
// coherence point), then one 16B chunk store per pair carrying the 1.
// Dependent post-screen traffic: 553MB -> ~25MB.
//
// Unchanged from R8 (proven exact, absmax 0.0 across R2-R15): fp32 top-2
// fmaf chain order, LDS s_cbf/s_c2f staging, BPT=2, grid (128,8) 4/CU,
// wave-cooperative fp64 repair of gap<=TAU2 pairs, cached stores, 32B
// embed stores from the LDS slice.

constexpr int B_  = 4096;
constexpr int C_  = 128;
constexpr int K_  = 256;
constexpr int D_  = 8;
constexpr int TPB = 256;

constexpr int   BPT   = 2;           // pairs per thread
constexpr int   BTILE = TPB * BPT;   // 512 b per block
constexpr float TAU2  = 1.0e-3f;     // ambiguity gap threshold

typedef float vf4 __attribute__((ext_vector_type(4)));

// Wave-cooperative exact fp64 re-argmin of ambiguous rows (identical to R8).
__device__ __forceinline__ void repair_amb(
    const float xfj[D_], int& k1j, const float s1j, const float s2j,
    const float* s_cbf, const int lane)
{
    const bool amb = (s2j - s1j) <= TAU2;
    unsigned long long mask = __ballot(amb);
    while (mask) {
        const int src = (int)__ffsll((long long)mask) - 1;
        mask &= mask - 1;
        double xd[D_];
        #pragma unroll
        for (int d = 0; d < D_; ++d) xd[d] = (double)__shfl(xfj[d], src);
        double best = 1.0e300;
        int    bk   = 0;
        #pragma unroll
        for (int t = 0; t < 4; ++t) {
            const int k = lane * 4 + t;      // ascending k within lane
            const float* cv = s_cbf + k * D_;
            double cd[D_];
            #pragma unroll
            for (int d = 0; d < D_; ++d) cd[d] = (double)cv[d];
            double c2k = 0.0;
            #pragma unroll
            for (int d = 0; d < D_; ++d) c2k = fma(cd[d], cd[d], c2k);
            double dot = xd[0] * cd[0];
            #pragma unroll
            for (int d = 1; d < D_; ++d) dot = fma(xd[d], cd[d], dot);
            const double score = fma(-2.0, dot, c2k);
            if (score < best) { best = score; bk = k; }  // first-min
        }
        #pragma unroll
        for (int off = 32; off >= 1; off >>= 1) {
            const double ob  = __shfl_down(best, off);
            const int    obk = __shfl_down(bk,   off);
            if (ob < best) { best = ob; bk = obk; }  // tie -> lower k
        }
        const int win = __shfl(bk, 0);
        if (lane == src) k1j = win;
    }
}

__global__ __launch_bounds__(TPB) void vq_fused(
    const float* __restrict__ x,
    const float* __restrict__ cb,
    float* __restrict__ out_embed,
    float* __restrict__ out_onehot)
{
    __shared__ float s_cbf[K_ * D_];  // 8 KB fp32 codebook slice
    __shared__ float s_c2f[K_];       // 1 KB fp32 ||c_k||^2

    const int c    = blockIdx.x;   // 0..127
    const int bt   = blockIdx.y;   // 0..7
    const int tid  = threadIdx.x;
    const int lane = tid & 63;
    const int wave = tid >> 6;

    // ---- stage codebook slice + c2 ----
    {
        const float4* gcb = (const float4*)(cb + (size_t)c * (K_ * D_));
        ((float4*)s_cbf)[tid]       = gcb[tid];
        ((float4*)s_cbf)[tid + TPB] = gcb[tid + TPB];
    }
    __syncthreads();
    {
        const float* v = s_cbf + tid * D_;
        float s = 0.f;
        #pragma unroll
        for (int d = 0; d < D_; ++d) s = fmaf(v[d], v[d], s);
        s_c2f[tid] = s;
    }
    __syncthreads();
    // LDS read-only below; k1 lives in registers — no more barriers.

    const float4* scb4 = (const float4*)s_cbf;
    const int bbase = bt * BTILE;

    // ---- x fragments ----
    float xf[BPT][D_];
    #pragma unroll
    for (int j = 0; j < BPT; ++j) {
        const int b = bbase + j * TPB + tid;
        const float4* xp = (const float4*)(x + (size_t)b * (C_ * D_) + c * D_);
        const float4 a = xp[0];
        const float4 h = xp[1];
        xf[j][0] = a.x; xf[j][1] = a.y; xf[j][2] = a.z; xf[j][3] = a.w;
        xf[j][4] = h.x; xf[j][5] = h.y; xf[j][6] = h.z; xf[j][7] = h.w;
    }

    // ---- fp32 top-2 screen with interleaved one-hot zero-bursts ----
    // One full-wave 1KB contiguous zero store per 2 k's (128 total/wave,
    // exactly the rows of this wave's lanes for both j) keeps HBM busy
    // during the otherwise store-free screen phase.
    float s1[BPT], s2[BPT];
    int   k1[BPT];
    #pragma unroll
    for (int j = 0; j < BPT; ++j) { s1[j] = 3.4e38f; s2[j] = 3.4e38f; k1[j] = 0; }

    const vf4 vzero = {0.f, 0.f, 0.f, 0.f};

    #pragma unroll 2
    for (int k = 0; k < K_; ++k) {
        const float4 clo = scb4[k * 2];
        const float4 chi = scb4[k * 2 + 1];
        const float  c2k = s_c2f[k];
        #pragma unroll
        for (int j = 0; j < BPT; ++j) {
            float dot = xf[j][0] * clo.x;
            dot = fmaf(xf[j][1], clo.y, dot);
            dot = fmaf(xf[j][2], clo.z, dot);
            dot = fmaf(xf[j][3], clo.w, dot);
            dot = fmaf(xf[j][4], chi.x, dot);
            dot = fmaf(xf[j][5], chi.y, dot);
            dot = fmaf(xf[j][6], chi.z, dot);
            dot = fmaf(xf[j][7], chi.w, dot);
            const float score = fmaf(-2.f, dot, c2k);
            // top-2 (s2 uses OLD s1; strict < keeps first-index winner)
            s2[j] = fminf(s2[j], fmaxf(score, s1[j]));
            const bool lt = score < s1[j];
            k1[j] = lt ? k : k1[j];
            s1[j] = lt ? score : s1[j];
        }
        if ((k & 1) == 0) {                  // static under unroll 2
            const int z  = k >> 1;           // 0..127
            const int jz = z >> 6;           // 0..1
            const int iz = z & 63;           // row within wave's group
            const int bw = bbase + jz * TPB + wave * 64;
            const size_t row = (size_t)(bw + iz) * C_ + c;
            ((vf4*)(out_onehot + row * K_))[lane] = vzero;
        }
    }

    // ---- inline fp64 repair of ambiguous pairs (wave-cooperative) ----
    #pragma unroll
    for (int j = 0; j < BPT; ++j) {
        repair_amb(xf[j], k1[j], s1[j], s2[j], s_cbf, lane);
    }

    // ---- embed writes (independent of zeros; overlap the zero drain) ----
    #pragma unroll
    for (int j = 0; j < BPT; ++j) {
        const int    b    = bbase + j * TPB + tid;
        const size_t pair = (size_t)b * C_ + c;
        float4* dst = (float4*)(out_embed + pair * D_);
        dst[0] = ((const float4*)s_cbf)[k1[j] * 2];
        dst[1] = ((const float4*)s_cbf)[k1[j] * 2 + 1];
    }

    // ---- drain zeros (same-wave same-address ordering), then the ones ----
    asm volatile("s_waitcnt vmcnt(0)" ::: "memory");

    #pragma unroll
    for (int j = 0; j < BPT; ++j) {
        const int    b   = bbase + j * TPB + tid;
        const size_t row = (size_t)b * C_ + c;
        const int    kk  = k1[j];
        const int    r   = kk & 3;
        vf4 v;
        v.x = (r == 0) ? 1.f : 0.f;
        v.y = (r == 1) ? 1.f : 0.f;
        v.z = (r == 2) ? 1.f : 0.f;
        v.w = (r == 3) ? 1.f : 0.f;
        ((vf4*)(out_onehot + row * K_))[kk >> 2] = v;
    }
}

extern "C" void kernel_launch(void* const* d_in, const int* in_sizes, int n_in,
                              void* d_out, int out_size, void* d_ws, size_t ws_size,
                              hipStream_t stream) {
    const float* x  = (const float*)d_in[0];
    const float* cb = (const float*)d_in[1];
    float* out        = (float*)d_out;
    float* out_embed  = out;                          // 4096*1024
    float* out_onehot = out + (size_t)B_ * C_ * D_;   // 4096*128*256

    dim3 grid(C_, B_ / BTILE);  // (128, 8) = 1024 blocks, 4 per CU
    vq_fused<<<grid, TPB, 0, stream>>>(x, cb, out_embed, out_onehot);
}

// Round 5
// 580.701 us; speedup vs baseline: 1.0552x; 1.0552x over previous
//
#include <hip/hip_runtime.h>

// VQ-VAE codebook quantization — R17: oversubscribed grid (BPT=1, 2048
// blocks) + XCD-aligned grid swizzle (linear = bt + 16*c -> XCD = bt%8).
// x: (4096, 1024) f32; codebook: (128, 256, 8) f32.
// out = [cw_embed (4096*1024 f32) | one_hot (4096*128*256 f32)].
//
// Post-mortems R13-R16: SMEM screen +42 (lgkmcnt serialization), readlane
// screen +25 (spills/hazards), BPT=4 +12 (fewer waves for store issue),
// zeros-early +31 (16B overwrites -> L2 partial-line RMW ~270MB extra).
// Surviving model: R8's write pattern is traffic-optimal; screen cost is
// not the exposed term. Untested mechanisms, both zero-extra-traffic:
//  (1) phase-lock: 1024 blocks = exactly resident -> all screen (HBM
//      idle) then all drain (VALU idle). Oversubscribe 2x (BPT=1, 2048
//      blocks, ~6-8 resident/CU): backfilled blocks screen under the
//      drain of retiring blocks.
//  (2) embed line (b, c..c+3) was written 32B-each by 4 blocks on 4
//      DIFFERENT XCDs (XCD=c%8) -> 4 partial-line HBM writebacks. With
//      grid(16 bt, 128 c): XCD = (bt+16c)%8 = bt%8 -> the 4 writers share
//      one L2 -> full-line merge; x-line refetch also consolidates.
//
// Unchanged (proven exact, absmax 0.0 across R2-R16): fp32 top-2 fmaf
// chain order, LDS s_cbf/s_c2f staging, wave-cooperative fp64 repair of
// gap<=TAU2 pairs, cached full-line one-hot bursts, 32B embed stores.

constexpr int B_  = 4096;
constexpr int C_  = 128;
constexpr int K_  = 256;
constexpr int D_  = 8;
constexpr int TPB = 256;

constexpr int   BPT   = 1;           // pairs per thread (R8: 2)
constexpr int   BTILE = TPB * BPT;   // 256 b per block
constexpr float TAU2  = 1.0e-3f;     // ambiguity gap threshold

typedef float vf4 __attribute__((ext_vector_type(4)));

// Wave-cooperative exact fp64 re-argmin of ambiguous rows (identical to R8).
__device__ __forceinline__ void repair_amb(
    const float xfj[D_], int& k1j, const float s1j, const float s2j,
    const float* s_cbf, const int lane)
{
    const bool amb = (s2j - s1j) <= TAU2;
    unsigned long long mask = __ballot(amb);
    while (mask) {
        const int src = (int)__ffsll((long long)mask) - 1;
        mask &= mask - 1;
        double xd[D_];
        #pragma unroll
        for (int d = 0; d < D_; ++d) xd[d] = (double)__shfl(xfj[d], src);
        double best = 1.0e300;
        int    bk   = 0;
        #pragma unroll
        for (int t = 0; t < 4; ++t) {
            const int k = lane * 4 + t;      // ascending k within lane
            const float* cv = s_cbf + k * D_;
            double cd[D_];
            #pragma unroll
            for (int d = 0; d < D_; ++d) cd[d] = (double)cv[d];
            double c2k = 0.0;
            #pragma unroll
            for (int d = 0; d < D_; ++d) c2k = fma(cd[d], cd[d], c2k);
            double dot = xd[0] * cd[0];
            #pragma unroll
            for (int d = 1; d < D_; ++d) dot = fma(xd[d], cd[d], dot);
            const double score = fma(-2.0, dot, c2k);
            if (score < best) { best = score; bk = k; }  // first-min
        }
        #pragma unroll
        for (int off = 32; off >= 1; off >>= 1) {
            const double ob  = __shfl_down(best, off);
            const int    obk = __shfl_down(bk,   off);
            if (ob < best) { best = ob; bk = obk; }  // tie -> lower k
        }
        const int win = __shfl(bk, 0);
        if (lane == src) k1j = win;
    }
}

__global__ __launch_bounds__(TPB) void vq_fused(
    const float* __restrict__ x,
    const float* __restrict__ cb,
    float* __restrict__ out_embed,
    float* __restrict__ out_onehot)
{
    __shared__ float s_cbf[K_ * D_];  // 8 KB fp32 codebook slice
    __shared__ float s_c2f[K_];       // 1 KB fp32 ||c_k||^2

    const int bt   = blockIdx.x;   // 0..15  (fast dim -> XCD = bt % 8)
    const int c    = blockIdx.y;   // 0..127
    const int tid  = threadIdx.x;
    const int lane = tid & 63;
    const int wave = tid >> 6;

    // ---- stage codebook slice + c2 ----
    {
        const float4* gcb = (const float4*)(cb + (size_t)c * (K_ * D_));
        ((float4*)s_cbf)[tid]       = gcb[tid];
        ((float4*)s_cbf)[tid + TPB] = gcb[tid + TPB];
    }
    __syncthreads();
    {
        const float* v = s_cbf + tid * D_;
        float s = 0.f;
        #pragma unroll
        for (int d = 0; d < D_; ++d) s = fmaf(v[d], v[d], s);
        s_c2f[tid] = s;
    }
    __syncthreads();
    // LDS read-only below; k1 lives in registers — no more barriers.

    const float4* scb4 = (const float4*)s_cbf;
    const int bbase = bt * BTILE;
    const int b     = bbase + tid;

    // ---- x fragment ----
    float xf[D_];
    {
        const float4* xp = (const float4*)(x + (size_t)b * (C_ * D_) + c * D_);
        const float4 a = xp[0];
        const float4 h = xp[1];
        xf[0] = a.x; xf[1] = a.y; xf[2] = a.z; xf[3] = a.w;
        xf[4] = h.x; xf[5] = h.y; xf[6] = h.z; xf[7] = h.w;
    }

    // ---- fp32 top-2 screen ----
    float s1 = 3.4e38f, s2 = 3.4e38f;
    int   k1 = 0;
    #pragma unroll 2
    for (int k = 0; k < K_; ++k) {
        const float4 clo = scb4[k * 2];
        const float4 chi = scb4[k * 2 + 1];
        const float  c2k = s_c2f[k];
        float dot = xf[0] * clo.x;
        dot = fmaf(xf[1], clo.y, dot);
        dot = fmaf(xf[2], clo.z, dot);
        dot = fmaf(xf[3], clo.w, dot);
        dot = fmaf(xf[4], chi.x, dot);
        dot = fmaf(xf[5], chi.y, dot);
        dot = fmaf(xf[6], chi.z, dot);
        dot = fmaf(xf[7], chi.w, dot);
        const float score = fmaf(-2.f, dot, c2k);
        // top-2 (s2 uses OLD s1; strict < keeps first-index winner)
        s2 = fminf(s2, fmaxf(score, s1));
        const bool lt = score < s1;
        k1 = lt ? k : k1;
        s1 = lt ? score : s1;
    }

    // ---- inline fp64 repair of ambiguous pairs (wave-cooperative) ----
    repair_amb(xf, k1, s1, s2, s_cbf, lane);

    // ---- writes (cached; full lines per 8 lanes, no RMW on one-hot) ----
    {
        // embed: own pair, 32B from LDS slice; the 4 c-adjacent writers of
        // each 128B line now share one XCD/L2 -> full-line merge.
        const size_t pair = (size_t)b * C_ + c;
        float4* dst = (float4*)(out_embed + pair * D_);
        dst[0] = ((const float4*)s_cbf)[k1 * 2];
        dst[1] = ((const float4*)s_cbf)[k1 * 2 + 1];

        // one-hot: wave writes its 64 lanes' rows; each store instruction is
        // one contiguous 1KB burst (16 full lines).
        const int bw = bbase + wave * 64;
        const int e0 = lane * 4;
        #pragma unroll 8
        for (int i = 0; i < 64; ++i) {
            const int k = __builtin_amdgcn_readlane(k1, i);
            vf4 v;
            v.x = (k == e0    ) ? 1.f : 0.f;
            v.y = (k == e0 + 1) ? 1.f : 0.f;
            v.z = (k == e0 + 2) ? 1.f : 0.f;
            v.w = (k == e0 + 3) ? 1.f : 0.f;
            const size_t row = (size_t)(bw + i) * C_ + c;
            ((vf4*)(out_onehot + row * K_))[lane] = v;
        }
    }
}

extern "C" void kernel_launch(void* const* d_in, const int* in_sizes, int n_in,
                              void* d_out, int out_size, void* d_ws, size_t ws_size,
                              hipStream_t stream) {
    const float* x  = (const float*)d_in[0];
    const float* cb = (const float*)d_in[1];
    float* out        = (float*)d_out;
    float* out_embed  = out;                          // 4096*1024
    float* out_onehot = out + (size_t)B_ * C_ * D_;   // 4096*128*256

    // bt fast, c slow: linear = bt + 16*c -> XCD = bt % 8; 2048 blocks,
    // ~6-8 resident/CU -> 2-3x oversubscription for screen/drain pipelining.
    dim3 grid(B_ / BTILE, C_);  // (16, 128)
    vq_fused<<<grid, TPB, 0, stream>>>(x, cb, out_embed, out_onehot);
}